// Round 4
// baseline (511.913 us; speedup 1.0000x reference)
//
#include <hip/hip_runtime.h>
#include <hip/hip_bf16.h>

#define N_ 16384
#define D_ 512
#define BM 256
#define BN 256
#define BK 64
#define NT (D_ / BK)    // 8 K-tiles
#define NBLK (N_ / BM)  // 64 blocks per dim
#define REGB 16384      // bytes per region: 256 rows x 32 cols bf16 (one kk-half)

typedef __attribute__((ext_vector_type(8))) __bf16 bf16x8;
typedef __attribute__((ext_vector_type(4))) float f32x4;

#define GLDS(gptr, lptr)                                                              \
  __builtin_amdgcn_global_load_lds((const __attribute__((address_space(1))) void*)(gptr), \
                                   (__attribute__((address_space(3))) void*)(lptr), 16, 0, 0)

#define MFMA(a, b, c) __builtin_amdgcn_mfma_f32_16x16x32_bf16((a), (b), (c), 0, 0, 0)

__device__ inline unsigned short f2bf(float f) {
  __hip_bfloat16 h = __float2bfloat16(f);
  return *reinterpret_cast<unsigned short*>(&h);
}

// ---------------- fp32 -> bf16 convert (vectorized), optional scale fold ----------------
__global__ void cvt_bf16_kernel(const float* __restrict__ src,
                                unsigned short* __restrict__ dst, long n,
                                const float* __restrict__ scale_p) {
  const float s = scale_p ? scale_p[0] : 1.0f;
  long i = ((long)blockIdx.x * blockDim.x + threadIdx.x) * 8;
  const long stride = (long)gridDim.x * blockDim.x * 8;
  typedef __attribute__((ext_vector_type(8))) unsigned short us8;
  for (; i < n; i += stride) {
    const float4* sp = (const float4*)(src + i);
    float4 f0 = sp[0], f1 = sp[1];
    us8 v;
    v[0] = f2bf(f0.x * s); v[1] = f2bf(f0.y * s); v[2] = f2bf(f0.z * s); v[3] = f2bf(f0.w * s);
    v[4] = f2bf(f1.x * s); v[5] = f2bf(f1.y * s); v[6] = f2bf(f1.z * s); v[7] = f2bf(f1.w * s);
    *(us8*)(dst + i) = v;
  }
}

// ---------------- 256x256 8-phase pipelined GEMM + row/col online-LSE partials ----------
// T3+T4: 4 phases per K-tile, each {ds_read subtile | stage 1 region | barrier |
// lgkmcnt(0) | 16 MFMA | barrier}; vmcnt(6) once per tile (ph4), vmcnt(0) only at last
// tile. Regions = kk-halves (16KB contiguous, linear GLDS dest); in-region chunk
// rotation (both-sides: inverse on global src, forward on ds_read) keeps reads
// conflict-free. T5: setprio around MFMA. T1: XCD-bijective block swizzle.
__global__ __launch_bounds__(512, 2)
void gemm_lse_kernel(const unsigned short* __restrict__ A,   // scale*img bf16 [N][D]
                     const unsigned short* __restrict__ B,   // txt bf16 [N][D]
                     float2* __restrict__ rowMS,  // [NBLK(colblk)][N] (max, sumexp)
                     float2* __restrict__ colMS,  // [NBLK(rowblk)][N]
                     float* __restrict__ diag) {
  // [slot][kk][256 rows][32 cols] bf16 per operand = 64 KiB each, 128 KiB total
  __shared__ __align__(16) unsigned short As[2][2][256][32];
  __shared__ __align__(16) unsigned short Bs[2][2][256][32];

  const int t = threadIdx.x;
  const int l = t & 63;
  const int wid = t >> 6;   // 0..7
  const int wr = wid >> 2;  // 0..1 : wave rows [wr*128, +128)
  const int wc = wid & 3;   // 0..3 : wave cols [wc*64, +64)

  int id = blockIdx.x;
  id = (id & 7) * (NBLK * NBLK / 8) + (id >> 3);
  const int br = id / NBLK;
  const int bc = id % NBLK;

  // stage decomposition: load L = t + p*512 writes region chunk L (16B);
  // chunk L holds global (row = L>>2, c16 = ((L&3) - (L>>3)) & 3)  [inverse rotation]
  const int sr0 = t >> 2;                        // rows 0..127 (+128 for p=1)
  const int sc0 = ((t & 3) - (t >> 3)) & 3;      // same for both p (128 ≡ 0 mod 4 after >>1)

  const unsigned short* aSt = A + (size_t)(br * BM + sr0) * D_ + sc0 * 8;
  const unsigned short* bSt = B + (size_t)(bc * BN + sr0) * D_ + sc0 * 8;

  // ds_read offsets: byte = row*64 + ((c16 + (row>>1)) & 3)*16, c16 = l>>4
  int offA[8], offB[4];
#pragma unroll
  for (int m = 0; m < 8; ++m) {
    const int row = wr * 128 + m * 16 + (l & 15);
    offA[m] = row * 64 + ((((l >> 4) + (row >> 1)) & 3) << 4);
  }
#pragma unroll
  for (int n = 0; n < 4; ++n) {
    const int row = wc * 64 + n * 16 + (l & 15);
    offB[n] = row * 64 + ((((l >> 4) + (row >> 1)) & 3) << 4);
  }

  f32x4 acc[8][4];
#pragma unroll
  for (int m = 0; m < 8; ++m)
#pragma unroll
    for (int n = 0; n < 4; ++n) acc[m][n] = (f32x4)0.0f;

  const char* asb = (const char*)As;
  const char* bsb = (const char*)Bs;
  bf16x8 af[8], bfv[4];

// stage one region (operand tile kt_, kk half K_) into slot S_: 2 GLDS/thread
#define STG(gbase, lds, S_, K_, kt_)                                   \
  {                                                                    \
    const unsigned short* g_ = (gbase) + (kt_)*BK + (K_)*32;           \
    char* d_ = (char*)(lds) + ((S_)*2 + (K_)) * REGB + t * 16;         \
    GLDS(g_, d_);                                                      \
    GLDS(g_ + 128 * D_, d_ + 8192);                                    \
  }

  // ---- prologue: tile0 {all 4 regions}, tile1 {Akk0,Bkk0,Akk1}; wait tile0 ----
  STG(aSt, As, 0, 0, 0); STG(bSt, Bs, 0, 0, 0);
  STG(aSt, As, 0, 1, 0); STG(bSt, Bs, 0, 1, 0);
  STG(aSt, As, 1, 0, 1); STG(bSt, Bs, 1, 0, 1);
  STG(aSt, As, 1, 1, 1);
  asm volatile("s_waitcnt vmcnt(6)" ::: "memory");
  __builtin_amdgcn_sched_barrier(0);
  __builtin_amdgcn_s_barrier();

#define PH_SYNC()                                          \
  __builtin_amdgcn_s_barrier();                            \
  asm volatile("s_waitcnt lgkmcnt(0)" ::: "memory");       \
  __builtin_amdgcn_sched_barrier(0);                       \
  __builtin_amdgcn_s_setprio(1);

#define PH_END()                                           \
  __builtin_amdgcn_s_setprio(0);                           \
  __builtin_amdgcn_s_barrier();

#define TILE(T_, S_)                                                          \
  {                                                                           \
    /* phase 1: kk0 x n{0,1} */                                               \
    _Pragma("unroll") for (int m = 0; m < 8; ++m)                             \
        af[m] = *(const bf16x8*)(asb + ((S_)*2 + 0) * REGB + offA[m]);        \
    bfv[0] = *(const bf16x8*)(bsb + ((S_)*2 + 0) * REGB + offB[0]);           \
    bfv[1] = *(const bf16x8*)(bsb + ((S_)*2 + 0) * REGB + offB[1]);           \
    if ((T_) + 1 < NT) STG(bSt, Bs, ((S_) ^ 1), 1, (T_) + 1);                 \
    if ((T_) == NT - 1) {                                                     \
      asm volatile("s_waitcnt vmcnt(0)" ::: "memory");                        \
      __builtin_amdgcn_sched_barrier(0);                                      \
    }                                                                         \
    PH_SYNC();                                                                \
    _Pragma("unroll") for (int m = 0; m < 8; ++m) {                           \
      acc[m][0] = MFMA(af[m], bfv[0], acc[m][0]);                             \
      acc[m][1] = MFMA(af[m], bfv[1], acc[m][1]);                             \
    }                                                                         \
    PH_END();                                                                 \
    /* phase 2: kk0 x n{2,3} */                                               \
    bfv[2] = *(const bf16x8*)(bsb + ((S_)*2 + 0) * REGB + offB[2]);           \
    bfv[3] = *(const bf16x8*)(bsb + ((S_)*2 + 0) * REGB + offB[3]);           \
    if ((T_) + 2 < NT) STG(aSt, As, (S_), 0, (T_) + 2);                       \
    PH_SYNC();                                                                \
    _Pragma("unroll") for (int m = 0; m < 8; ++m) {                           \
      acc[m][2] = MFMA(af[m], bfv[2], acc[m][2]);                             \
      acc[m][3] = MFMA(af[m], bfv[3], acc[m][3]);                             \
    }                                                                         \
    PH_END();                                                                 \
    /* phase 3: kk1 x n{0,1} */                                               \
    _Pragma("unroll") for (int m = 0; m < 8; ++m)                             \
        af[m] = *(const bf16x8*)(asb + ((S_)*2 + 1) * REGB + offA[m]);        \
    bfv[0] = *(const bf16x8*)(bsb + ((S_)*2 + 1) * REGB + offB[0]);           \
    bfv[1] = *(const bf16x8*)(bsb + ((S_)*2 + 1) * REGB + offB[1]);           \
    if ((T_) + 2 < NT) STG(bSt, Bs, (S_), 0, (T_) + 2);                       \
    PH_SYNC();                                                                \
    _Pragma("unroll") for (int m = 0; m < 8; ++m) {                           \
      acc[m][0] = MFMA(af[m], bfv[0], acc[m][0]);                             \
      acc[m][1] = MFMA(af[m], bfv[1], acc[m][1]);                             \
    }                                                                         \
    PH_END();                                                                 \
    /* phase 4: kk1 x n{2,3} */                                               \
    bfv[2] = *(const bf16x8*)(bsb + ((S_)*2 + 1) * REGB + offB[2]);           \
    bfv[3] = *(const bf16x8*)(bsb + ((S_)*2 + 1) * REGB + offB[3]);           \
    if ((T_) + 2 < NT) STG(aSt, As, (S_), 1, (T_) + 2);                       \
    asm volatile("s_waitcnt vmcnt(6)" ::: "memory");                          \
    __builtin_amdgcn_sched_barrier(0);                                        \
    PH_SYNC();                                                                \
    _Pragma("unroll") for (int m = 0; m < 8; ++m) {                           \
      acc[m][2] = MFMA(af[m], bfv[2], acc[m][2]);                             \
      acc[m][3] = MFMA(af[m], bfv[3], acc[m][3]);                             \
    }                                                                         \
    PH_END();                                                                 \
  }

#pragma unroll 1
  for (int tp = 0; tp < NT; tp += 2) {
    TILE(tp, 0);
    TILE(tp + 1, 1);
  }
#undef TILE
#undef PH_SYNC
#undef PH_END
#undef STG

  // ---- epilogue: diag, row/col online-LSE partials; reuse As as merge scratch ----
  float* rowb = (float*)As;            // [4][256][2] floats (8 KiB)
  float* colb = rowb + 4 * 256 * 2;    // [2][256][2] floats (4 KiB)

  if (br == bc) {
#pragma unroll
    for (int m = 0; m < 8; ++m)
#pragma unroll
      for (int n = 0; n < 4; ++n)
#pragma unroll
        for (int r = 0; r < 4; ++r) {
          const int row = wr * 128 + m * 16 + (l >> 4) * 4 + r;
          const int col = wc * 64 + n * 16 + (l & 15);
          if (row == col) diag[br * BM + row] = acc[m][n][r];
        }
  }

  // ROW pass: row = wr*128 + m*16 + (l>>4)*4 + r; its 64 cols = {n} x 16 lanes (l&15)
#pragma unroll
  for (int m = 0; m < 8; ++m) {
#pragma unroll
    for (int r = 0; r < 4; ++r) {
      float mx = fmaxf(fmaxf(acc[m][0][r], acc[m][1][r]), fmaxf(acc[m][2][r], acc[m][3][r]));
#pragma unroll
      for (int off = 1; off < 16; off <<= 1) mx = fmaxf(mx, __shfl_xor(mx, off, 64));
      float s = 0.f;
#pragma unroll
      for (int n = 0; n < 4; ++n) s += __expf(acc[m][n][r] - mx);
#pragma unroll
      for (int off = 1; off < 16; off <<= 1) s += __shfl_xor(s, off, 64);
      if ((l & 15) == 0) {
        const int row = wr * 128 + m * 16 + (l >> 4) * 4 + r;
        rowb[(wc * 256 + row) * 2 + 0] = mx;
        rowb[(wc * 256 + row) * 2 + 1] = s;
      }
    }
  }

  // COL pass: col = wc*64 + n*16 + (l&15); its 128 rows = {m,r} x 4 lane-groups (l>>4)
#pragma unroll
  for (int n = 0; n < 4; ++n) {
    float mx = -1e30f;
#pragma unroll
    for (int m = 0; m < 8; ++m)
#pragma unroll
      for (int r = 0; r < 4; ++r) mx = fmaxf(mx, acc[m][n][r]);
    mx = fmaxf(mx, __shfl_xor(mx, 16, 64));
    mx = fmaxf(mx, __shfl_xor(mx, 32, 64));
    float s = 0.f;
#pragma unroll
    for (int m = 0; m < 8; ++m)
#pragma unroll
      for (int r = 0; r < 4; ++r) s += __expf(acc[m][n][r] - mx);
    s += __shfl_xor(s, 16, 64);
    s += __shfl_xor(s, 32, 64);
    if ((l >> 4) == 0) {
      const int col = wc * 64 + n * 16 + l;
      colb[(wr * 256 + col) * 2 + 0] = mx;
      colb[(wr * 256 + col) * 2 + 1] = s;
    }
  }
  __syncthreads();

  // merge wave-halves, write partials (coalesced float2)
  if (t < 256) {
    float mm = -1e30f, ss = 0.f;
#pragma unroll
    for (int w = 0; w < 4; ++w) {
      float m0 = rowb[(w * 256 + t) * 2 + 0], s0 = rowb[(w * 256 + t) * 2 + 1];
      float nm = fmaxf(mm, m0);
      ss = ss * __expf(mm - nm) + s0 * __expf(m0 - nm);
      mm = nm;
    }
    rowMS[(size_t)bc * N_ + br * BM + t] = make_float2(mm, ss);
  } else {
    const int c = t - 256;
    float mm = -1e30f, ss = 0.f;
#pragma unroll
    for (int w = 0; w < 2; ++w) {
      float m0 = colb[(w * 256 + c) * 2 + 0], s0 = colb[(w * 256 + c) * 2 + 1];
      float nm = fmaxf(mm, m0);
      ss = ss * __expf(mm - nm) + s0 * __expf(m0 - nm);
      mm = nm;
    }
    colMS[(size_t)br * N_ + bc * BN + c] = make_float2(mm, ss);
  }
}

// ---------------- merge partials -> per-row/col LSE -> partial sums ----------------
__global__ void reduce1_kernel(const float2* __restrict__ rowMS,
                               const float2* __restrict__ colMS,
                               const float* __restrict__ diag,
                               float* __restrict__ partials) {
  const int tid = blockIdx.x * blockDim.x + threadIdx.x;  // 0..32767
  float m = -1e30f, s = 0.f;
  if (tid < N_) {
    const int r = tid;
    for (int cb = 0; cb < NBLK; ++cb) {
      float2 p = rowMS[(size_t)cb * N_ + r];
      float nm = fmaxf(m, p.x);
      s = s * __expf(m - nm) + p.y * __expf(p.x - nm);
      m = nm;
    }
    m = m + logf(s) - diag[r];
  } else {
    const int c = tid - N_;
    for (int rb = 0; rb < NBLK; ++rb) {
      float2 p = colMS[(size_t)rb * N_ + c];
      float nm = fmaxf(m, p.x);
      s = s * __expf(m - nm) + p.y * __expf(p.x - nm);
      m = nm;
    }
    m = m + logf(s) - diag[c];
  }
  float val = m;
#pragma unroll
  for (int off = 1; off < 64; off <<= 1) val += __shfl_xor(val, off, 64);
  __shared__ float red[4];
  if ((threadIdx.x & 63) == 0) red[threadIdx.x >> 6] = val;
  __syncthreads();
  if (threadIdx.x == 0) partials[blockIdx.x] = red[0] + red[1] + red[2] + red[3];
}

__global__ void reduce2_kernel(const float* __restrict__ partials, float* __restrict__ out) {
  const int t = threadIdx.x;  // 64 threads
  float v = partials[t] + partials[t + 64];
#pragma unroll
  for (int off = 1; off < 64; off <<= 1) v += __shfl_xor(v, off, 64);
  if (t == 0) out[0] = v * (1.0f / (2.0f * (float)N_));
}

extern "C" void kernel_launch(void* const* d_in, const int* in_sizes, int n_in,
                              void* d_out, int out_size, void* d_ws, size_t ws_size,
                              hipStream_t stream) {
  const float* img = (const float*)d_in[0];
  const float* txt = (const float*)d_in[1];
  const float* scale = (const float*)d_in[2];
  float* out = (float*)d_out;

  char* ws = (char*)d_ws;
  size_t off = 0;
  unsigned short* imgB = (unsigned short*)(ws + off); off += (size_t)N_ * D_ * 2;
  unsigned short* txtB = (unsigned short*)(ws + off); off += (size_t)N_ * D_ * 2;
  float2* rowMS = (float2*)(ws + off); off += (size_t)NBLK * N_ * sizeof(float2);
  float2* colMS = (float2*)(ws + off); off += (size_t)NBLK * N_ * sizeof(float2);
  float* diag = (float*)(ws + off); off += (size_t)N_ * sizeof(float);
  float* partials = (float*)(ws + off); off += 128 * sizeof(float);
  (void)ws_size; (void)in_sizes; (void)n_in; (void)out_size;

  cvt_bf16_kernel<<<1024, 256, 0, stream>>>(img, imgB, (long)N_ * D_, scale);
  cvt_bf16_kernel<<<1024, 256, 0, stream>>>(txt, txtB, (long)N_ * D_, nullptr);
  gemm_lse_kernel<<<NBLK * NBLK, 512, 0, stream>>>(imgB, txtB, rowMS, colMS, diag);
  reduce1_kernel<<<(2 * N_) / 256, 256, 0, stream>>>(rowMS, colMS, diag, partials);
  reduce2_kernel<<<1, 64, 0, stream>>>(partials, out);
}

// Round 5
// 481.954 us; speedup vs baseline: 1.0622x; 1.0622x over previous
//
#include <hip/hip_runtime.h>
#include <hip/hip_bf16.h>

#define N_ 16384
#define D_ 512
#define BM 128
#define BN 128
#define BK 32
#define NT (D_ / BK)    // 16 K-tiles
#define NBLK (N_ / BM)  // 128 blocks per dim
#define BUFB 8192       // bytes per LDS buffer (128*32*2)

typedef __attribute__((ext_vector_type(8))) __bf16 bf16x8;
typedef __attribute__((ext_vector_type(4))) float f32x4;

#define GLDS(gptr, lptr)                                                              \
  __builtin_amdgcn_global_load_lds((const __attribute__((address_space(1))) void*)(gptr), \
                                   (__attribute__((address_space(3))) void*)(lptr), 16, 0, 0)

#define MFMA16(a, b, c) __builtin_amdgcn_mfma_f32_16x16x32_bf16((a), (b), (c), 0, 0, 0)

__device__ inline unsigned short f2bf(float f) {
  __hip_bfloat16 h = __float2bfloat16(f);
  return *reinterpret_cast<unsigned short*>(&h);
}

// ---------------- fp32 -> bf16 convert (vectorized), optional scale fold ----------------
// img gets scale * log2(e) folded in -> all downstream exp/log run in base-2 domain
// (pure v_exp_f32 / v_log_f32, no mul). Final loss multiplies by ln2.
__global__ void cvt_bf16_kernel(const float* __restrict__ src,
                                unsigned short* __restrict__ dst, long n,
                                const float* __restrict__ scale_p) {
  const float s = scale_p ? scale_p[0] * 1.4426950408889634f : 1.0f;
  long i = ((long)blockIdx.x * blockDim.x + threadIdx.x) * 8;
  const long stride = (long)gridDim.x * blockDim.x * 8;
  typedef __attribute__((ext_vector_type(8))) unsigned short us8;
  for (; i < n; i += stride) {
    const float4* sp = (const float4*)(src + i);
    float4 f0 = sp[0], f1 = sp[1];
    us8 v;
    v[0] = f2bf(f0.x * s); v[1] = f2bf(f0.y * s); v[2] = f2bf(f0.z * s); v[3] = f2bf(f0.w * s);
    v[4] = f2bf(f1.x * s); v[5] = f2bf(f1.y * s); v[6] = f2bf(f1.z * s); v[7] = f2bf(f1.w * s);
    *(us8*)(dst + i) = v;
  }
}

// ---------------- 128x128 2-phase double-buffered GEMM + row/col LSE partials ----------
// Catalog T3-minimum recipe (m248v2-verified): per tile {STAGE(next) ; ds_read(cur) ;
// MFMA ; __syncthreads (= vmcnt(0)+lgkm(0)+barrier)}. Stage latency hides under the
// tile's own compute; ONE barrier per tile. BK=32 keeps dbuf LDS at 32KB -> 4 blocks/CU
// (R2's proven occupancy). At BK=32 the natural [row][32] layout is bank-balanced
// (slot=(row&1)*4+c16, 8 lanes/slot = min) -> no swizzle on either side.
__global__ __launch_bounds__(256, 4)
void gemm_lse_kernel(const unsigned short* __restrict__ A,   // log2e*scale*img bf16 [N][D]
                     const unsigned short* __restrict__ B,   // txt bf16 [N][D]
                     float2* __restrict__ rowMS,  // [NBLK(colblk)][N] (max, sumexp) base-2
                     float2* __restrict__ colMS,  // [NBLK(rowblk)][N]
                     float* __restrict__ diag) {
  __shared__ __align__(16) unsigned short As[2][BM][BK];  // 16 KiB
  __shared__ __align__(16) unsigned short Bs[2][BN][BK];  // 16 KiB
  __shared__ float rowbuf[2][BM][2];
  __shared__ float colbuf[2][BN][2];

  const int t = threadIdx.x;
  const int l = t & 63;
  const int wid = t >> 6;
  const int wr = wid >> 1;   // wave row (0..1), wave tile 64x64
  const int wc = wid & 1;    // wave col

  // XCD-aware bijective swizzle (nwg = 16384, divisible by 8)
  int id = blockIdx.x;
  id = (id & 7) * (NBLK * NBLK / 8) + (id >> 3);
  const int br = id / NBLK;
  const int bc = id % NBLK;

  // staging: thread t stages 16B chunks t and t+256 (linear dest, linear source)
  const int srow = t >> 2;        // 0..63 (+64 for second chunk)
  const int scol = (t & 3) * 8;   // elements

  const unsigned short* aBase = A + (size_t)(br * BM + srow) * D_ + scol;
  const unsigned short* bBase = B + (size_t)(bc * BN + srow) * D_ + scol;

  f32x4 acc[4][4];
#pragma unroll
  for (int m = 0; m < 4; ++m)
#pragma unroll
    for (int n = 0; n < 4; ++n) acc[m][n] = (f32x4)0.0f;

#define STAGE(kt_, b_)                                   \
  {                                                      \
    const unsigned short* ag_ = aBase + (kt_)*BK;        \
    const unsigned short* bg_ = bBase + (kt_)*BK;        \
    char* al_ = (char*)As + (b_)*BUFB + t * 16;          \
    char* bl_ = (char*)Bs + (b_)*BUFB + t * 16;          \
    GLDS(ag_, al_);                                      \
    GLDS(ag_ + 64 * D_, al_ + 4096);                     \
    GLDS(bg_, bl_);                                      \
    GLDS(bg_ + 64 * D_, bl_ + 4096);                     \
  }

  STAGE(0, 0);
  __syncthreads();  // drains vmcnt(0): tile 0 ready

#pragma unroll
  for (int kt = 0; kt < NT; ++kt) {
    const int cur = kt & 1;
    if (kt + 1 < NT) STAGE(kt + 1, cur ^ 1);  // issue next-tile loads FIRST
    bf16x8 af[4], bfv[4];
#pragma unroll
    for (int m = 0; m < 4; ++m)
      af[m] = *(const bf16x8*)&As[cur][wr * 64 + m * 16 + (l & 15)][(l >> 4) * 8];
#pragma unroll
    for (int n = 0; n < 4; ++n)
      bfv[n] = *(const bf16x8*)&Bs[cur][wc * 64 + n * 16 + (l & 15)][(l >> 4) * 8];
    __builtin_amdgcn_s_setprio(1);
#pragma unroll
    for (int m = 0; m < 4; ++m)
#pragma unroll
      for (int n = 0; n < 4; ++n)
        acc[m][n] = MFMA16(af[m], bfv[n], acc[m][n]);
    __builtin_amdgcn_s_setprio(0);
    __syncthreads();  // = s_waitcnt vmcnt(0) lgkmcnt(0); s_barrier  -> next tile ready
  }
#undef STAGE

  // ---- epilogue (base-2 domain): diag, row/col online-LSE partials ----
  // C/D layout (m89-verified): col = l&15, row = (l>>4)*4 + r  (within 16x16 frag)
  if (br == bc && wr == wc) {
#pragma unroll
    for (int m = 0; m < 4; ++m)
#pragma unroll
      for (int r = 0; r < 4; ++r)
        if ((l & 15) == ((l >> 4) * 4 + r))
          diag[br * BM + wr * 64 + m * 16 + (l & 15)] = acc[m][m][r];
  }

  // ROW pass: row = wr*64 + m*16 + (l>>4)*4 + r ; its 64 cols = {n} x 16 lanes (l&15)
#pragma unroll
  for (int m = 0; m < 4; ++m) {
#pragma unroll
    for (int r = 0; r < 4; ++r) {
      float mx = fmaxf(fmaxf(acc[m][0][r], acc[m][1][r]), fmaxf(acc[m][2][r], acc[m][3][r]));
#pragma unroll
      for (int off = 1; off < 16; off <<= 1) mx = fmaxf(mx, __shfl_xor(mx, off, 64));
      float s = 0.f;
#pragma unroll
      for (int n = 0; n < 4; ++n) s += exp2f(acc[m][n][r] - mx);
#pragma unroll
      for (int off = 1; off < 16; off <<= 1) s += __shfl_xor(s, off, 64);
      if ((l & 15) == 0) {
        const int row = wr * 64 + m * 16 + (l >> 4) * 4 + r;
        rowbuf[wc][row][0] = mx;
        rowbuf[wc][row][1] = s;
      }
    }
  }

  // COL pass: col = wc*64 + n*16 + (l&15); its 64 rows = {m,r} x 4 lane-groups (l>>4)
#pragma unroll
  for (int n = 0; n < 4; ++n) {
    float mx = -1e30f;
#pragma unroll
    for (int m = 0; m < 4; ++m)
#pragma unroll
      for (int r = 0; r < 4; ++r) mx = fmaxf(mx, acc[m][n][r]);
    mx = fmaxf(mx, __shfl_xor(mx, 16, 64));
    mx = fmaxf(mx, __shfl_xor(mx, 32, 64));
    float s = 0.f;
#pragma unroll
    for (int m = 0; m < 4; ++m)
#pragma unroll
      for (int r = 0; r < 4; ++r) s += exp2f(acc[m][n][r] - mx);
    s += __shfl_xor(s, 16, 64);
    s += __shfl_xor(s, 32, 64);
    if ((l >> 4) == 0) {
      const int col = wc * 64 + n * 16 + l;
      colbuf[wr][col][0] = mx;
      colbuf[wr][col][1] = s;
    }
  }
  __syncthreads();

  // merge the two wave-halves, write partials (coalesced float2)
  if (t < BM) {
    float m0 = rowbuf[0][t][0], s0 = rowbuf[0][t][1];
    float m1 = rowbuf[1][t][0], s1 = rowbuf[1][t][1];
    float mm = fmaxf(m0, m1);
    float ss = s0 * exp2f(m0 - mm) + s1 * exp2f(m1 - mm);
    rowMS[(size_t)bc * N_ + br * BM + t] = make_float2(mm, ss);
  } else {
    const int c = t - BM;
    float m0 = colbuf[0][c][0], s0 = colbuf[0][c][1];
    float m1 = colbuf[1][c][0], s1 = colbuf[1][c][1];
    float mm = fmaxf(m0, m1);
    float ss = s0 * exp2f(m0 - mm) + s1 * exp2f(m1 - mm);
    colMS[(size_t)br * N_ + bc * BN + c] = make_float2(mm, ss);
  }
}

// ---------------- merge partials -> per-row/col LSE2 -> partial sums (base-2) ----------
__global__ void reduce1_kernel(const float2* __restrict__ rowMS,
                               const float2* __restrict__ colMS,
                               const float* __restrict__ diag,
                               float* __restrict__ partials) {
  const int tid = blockIdx.x * blockDim.x + threadIdx.x;  // 0..32767
  float m = -1e30f, s = 0.f;
  if (tid < N_) {
    const int r = tid;
    for (int cb = 0; cb < NBLK; ++cb) {
      float2 p = rowMS[(size_t)cb * N_ + r];
      float nm = fmaxf(m, p.x);
      s = s * exp2f(m - nm) + p.y * exp2f(p.x - nm);
      m = nm;
    }
    m = m + log2f(s) - diag[r];
  } else {
    const int c = tid - N_;
    for (int rb = 0; rb < NBLK; ++rb) {
      float2 p = colMS[(size_t)rb * N_ + c];
      float nm = fmaxf(m, p.x);
      s = s * exp2f(m - nm) + p.y * exp2f(p.x - nm);
      m = nm;
    }
    m = m + log2f(s) - diag[c];
  }
  float val = m;
#pragma unroll
  for (int off = 1; off < 64; off <<= 1) val += __shfl_xor(val, off, 64);
  __shared__ float red[4];
  if ((threadIdx.x & 63) == 0) red[threadIdx.x >> 6] = val;
  __syncthreads();
  if (threadIdx.x == 0) partials[blockIdx.x] = red[0] + red[1] + red[2] + red[3];
}

__global__ void reduce2_kernel(const float* __restrict__ partials, float* __restrict__ out) {
  const int t = threadIdx.x;  // 64 threads
  float v = partials[t] + partials[t + 64];
#pragma unroll
  for (int off = 1; off < 64; off <<= 1) v += __shfl_xor(v, off, 64);
  // base-2 -> natural log: x ln2 ; mean over rows+cols and the 0.5 factor
  if (t == 0) out[0] = v * (0.69314718055994531f / (2.0f * (float)N_));
}

extern "C" void kernel_launch(void* const* d_in, const int* in_sizes, int n_in,
                              void* d_out, int out_size, void* d_ws, size_t ws_size,
                              hipStream_t stream) {
  const float* img = (const float*)d_in[0];
  const float* txt = (const float*)d_in[1];
  const float* scale = (const float*)d_in[2];
  float* out = (float*)d_out;

  char* ws = (char*)d_ws;
  size_t off = 0;
  unsigned short* imgB = (unsigned short*)(ws + off); off += (size_t)N_ * D_ * 2;
  unsigned short* txtB = (unsigned short*)(ws + off); off += (size_t)N_ * D_ * 2;
  float2* rowMS = (float2*)(ws + off); off += (size_t)NBLK * N_ * sizeof(float2);
  float2* colMS = (float2*)(ws + off); off += (size_t)NBLK * N_ * sizeof(float2);
  float* diag = (float*)(ws + off); off += (size_t)N_ * sizeof(float);
  float* partials = (float*)(ws + off); off += 128 * sizeof(float);
  (void)ws_size; (void)in_sizes; (void)n_in; (void)out_size;

  cvt_bf16_kernel<<<1024, 256, 0, stream>>>(img, imgB, (long)N_ * D_, scale);
  cvt_bf16_kernel<<<1024, 256, 0, stream>>>(txt, txtB, (long)N_ * D_, nullptr);
  gemm_lse_kernel<<<NBLK * NBLK, 256, 0, stream>>>(imgB, txtB, rowMS, colMS, diag);
  reduce1_kernel<<<(2 * N_) / 256, 256, 0, stream>>>(rowMS, colMS, diag, partials);
  reduce2_kernel<<<1, 64, 0, stream>>>(partials, out);
}

// Round 6
// 436.657 us; speedup vs baseline: 1.1723x; 1.1037x over previous
//
#include <hip/hip_runtime.h>
#include <hip/hip_bf16.h>

#define N_ 16384
#define D_ 512
#define BM 128
#define BN 128
#define BK 32
#define NT (D_ / BK)    // 16 K-tiles
#define NBLK (N_ / BM)  // 128 blocks per dim
#define BUFB 8192       // bytes per LDS buffer (128*32*2)

typedef __attribute__((ext_vector_type(8))) __bf16 bf16x8;
typedef __attribute__((ext_vector_type(4))) float f32x4;

#define GLDS(gptr, lptr)                                                              \
  __builtin_amdgcn_global_load_lds((const __attribute__((address_space(1))) void*)(gptr), \
                                   (__attribute__((address_space(3))) void*)(lptr), 16, 0, 0)

#define MFMA16(a, b, c) __builtin_amdgcn_mfma_f32_16x16x32_bf16((a), (b), (c), 0, 0, 0)

__device__ inline unsigned short f2bf(float f) {
  __hip_bfloat16 h = __float2bfloat16(f);
  return *reinterpret_cast<unsigned short*>(&h);
}

// ---------------- fp32 -> bf16 convert (vectorized), optional scale fold ----------------
// img gets scale * log2(e) folded in -> downstream exp/log run in base-2 domain.
__global__ void cvt_bf16_kernel(const float* __restrict__ src,
                                unsigned short* __restrict__ dst, long n,
                                const float* __restrict__ scale_p) {
  const float s = scale_p ? scale_p[0] * 1.4426950408889634f : 1.0f;
  long i = ((long)blockIdx.x * blockDim.x + threadIdx.x) * 8;
  const long stride = (long)gridDim.x * blockDim.x * 8;
  typedef __attribute__((ext_vector_type(8))) unsigned short us8;
  for (; i < n; i += stride) {
    const float4* sp = (const float4*)(src + i);
    float4 f0 = sp[0], f1 = sp[1];
    us8 v;
    v[0] = f2bf(f0.x * s); v[1] = f2bf(f0.y * s); v[2] = f2bf(f0.z * s); v[3] = f2bf(f0.w * s);
    v[4] = f2bf(f1.x * s); v[5] = f2bf(f1.y * s); v[6] = f2bf(f1.z * s); v[7] = f2bf(f1.w * s);
    *(us8*)(dst + i) = v;
  }
}

// ---------------- 128x128 2-phase double-buffered GEMM + row/col LSE partials ----------
// dbuf recipe (T3-minimum) + corrected BK=32 swizzle: LDS slot (row,s) holds global
// (row, s ^ ((row>>1)&3)); linear GLDS dest, inverse-permuted global src, XOR'd read.
// Quarter-wave (16-lane) b128 reads then cover all 8 bank slots -> conflict-free.
// Block mapping: each XCD owns a 16-wide bc stripe (B L2-resident, 2MB) and sweeps
// br slowly (A via L3) -> HBM fetch should collapse vs 1.06 GB.
__global__ __launch_bounds__(256, 4)
void gemm_lse_kernel(const unsigned short* __restrict__ A,   // log2e*scale*img bf16 [N][D]
                     const unsigned short* __restrict__ B,   // txt bf16 [N][D]
                     float2* __restrict__ rowMS,  // [NBLK(colblk)][N] (max, sumexp) base-2
                     float2* __restrict__ colMS,  // [NBLK(rowblk)][N]
                     float* __restrict__ diag) {
  __shared__ __align__(16) unsigned short As[2][BM][BK];  // 16 KiB
  __shared__ __align__(16) unsigned short Bs[2][BN][BK];  // 16 KiB
  __shared__ float rowbuf[2][BM][2];
  __shared__ float colbuf[2][BN][2];

  const int t = threadIdx.x;
  const int l = t & 63;
  const int wid = t >> 6;
  const int wr = wid >> 1;   // wave row (0..1), wave tile 64x64
  const int wc = wid & 1;    // wave col

  // L2-resident mapping: XCD x owns bc in [x*16, x*16+16); br advances every 16 blocks.
  const int id = blockIdx.x;
  const int w = id >> 3;
  const int bc = (id & 7) * 16 + (w & 15);
  const int br = w >> 4;

  // staging: thread t stages 16B chunks t and t+256 (linear LDS dest).
  // LDS(row, s) must hold global (row, s ^ ((row>>1)&3)):
  //   dest row = t>>2, slot = t&3  ->  src col chunk = (t&3) ^ ((t>>3)&3).
  // (second chunk: row += 64, (row>>1)&3 unchanged since 64>>1 = 32 ≡ 0 mod 4)
  const int srow = t >> 2;
  const int scol = ((t & 3) ^ ((t >> 3) & 3)) * 8;  // elements

  const unsigned short* aBase = A + (size_t)(br * BM + srow) * D_ + scol;
  const unsigned short* bBase = B + (size_t)(bc * BN + srow) * D_ + scol;

  f32x4 acc[4][4];
#pragma unroll
  for (int m = 0; m < 4; ++m)
#pragma unroll
    for (int n = 0; n < 4; ++n) acc[m][n] = (f32x4)0.0f;

  // read offsets: global (row, c16=l>>4) lives at LDS byte row*64 + (c16^((row>>1)&3))*16
  int offA[4], offB[4];
#pragma unroll
  for (int m = 0; m < 4; ++m) {
    const int rowA = wr * 64 + m * 16 + (l & 15);
    offA[m] = rowA * 64 + ((((l >> 4) ^ (rowA >> 1)) & 3) << 4);
    const int rowB = wc * 64 + m * 16 + (l & 15);
    offB[m] = rowB * 64 + ((((l >> 4) ^ (rowB >> 1)) & 3) << 4);
  }
  const char* asb = (const char*)As;
  const char* bsb = (const char*)Bs;

#define STAGE(kt_, b_)                                   \
  {                                                      \
    const unsigned short* ag_ = aBase + (kt_)*BK;        \
    const unsigned short* bg_ = bBase + (kt_)*BK;        \
    char* al_ = (char*)As + (b_)*BUFB + t * 16;          \
    char* bl_ = (char*)Bs + (b_)*BUFB + t * 16;          \
    GLDS(ag_, al_);                                      \
    GLDS(ag_ + 64 * D_, al_ + 4096);                     \
    GLDS(bg_, bl_);                                      \
    GLDS(bg_ + 64 * D_, bl_ + 4096);                     \
  }

  STAGE(0, 0);
  __syncthreads();  // drains vmcnt(0): tile 0 ready

#pragma unroll
  for (int kt = 0; kt < NT; ++kt) {
    const int cur = kt & 1;
    if (kt + 1 < NT) STAGE(kt + 1, cur ^ 1);  // issue next-tile loads FIRST
    bf16x8 af[4], bfv[4];
#pragma unroll
    for (int m = 0; m < 4; ++m) {
      af[m] = *(const bf16x8*)(asb + cur * BUFB + offA[m]);
      bfv[m] = *(const bf16x8*)(bsb + cur * BUFB + offB[m]);
    }
    __builtin_amdgcn_s_setprio(1);
#pragma unroll
    for (int m = 0; m < 4; ++m)
#pragma unroll
      for (int n = 0; n < 4; ++n)
        acc[m][n] = MFMA16(af[m], bfv[n], acc[m][n]);
    __builtin_amdgcn_s_setprio(0);
    __syncthreads();  // = vmcnt(0)+lgkmcnt(0)+barrier -> next tile ready
  }
#undef STAGE

  // ---- epilogue (base-2 domain): diag, row/col online-LSE partials ----
  // C/D layout (m89-verified): col = l&15, row = (l>>4)*4 + r  (within 16x16 frag)
  if (br == bc && wr == wc) {
#pragma unroll
    for (int m = 0; m < 4; ++m)
#pragma unroll
      for (int r = 0; r < 4; ++r)
        if ((l & 15) == ((l >> 4) * 4 + r))
          diag[br * BM + wr * 64 + m * 16 + (l & 15)] = acc[m][m][r];
  }

  // ROW pass: row = wr*64 + m*16 + (l>>4)*4 + r ; its 64 cols = {n} x 16 lanes (l&15)
#pragma unroll
  for (int m = 0; m < 4; ++m) {
#pragma unroll
    for (int r = 0; r < 4; ++r) {
      float mx = fmaxf(fmaxf(acc[m][0][r], acc[m][1][r]), fmaxf(acc[m][2][r], acc[m][3][r]));
#pragma unroll
      for (int off = 1; off < 16; off <<= 1) mx = fmaxf(mx, __shfl_xor(mx, off, 64));
      float s = 0.f;
#pragma unroll
      for (int n = 0; n < 4; ++n) s += exp2f(acc[m][n][r] - mx);
#pragma unroll
      for (int off = 1; off < 16; off <<= 1) s += __shfl_xor(s, off, 64);
      if ((l & 15) == 0) {
        const int row = wr * 64 + m * 16 + (l >> 4) * 4 + r;
        rowbuf[wc][row][0] = mx;
        rowbuf[wc][row][1] = s;
      }
    }
  }

  // COL pass: col = wc*64 + n*16 + (l&15); its 64 rows = {m,r} x 4 lane-groups (l>>4)
#pragma unroll
  for (int n = 0; n < 4; ++n) {
    float mx = -1e30f;
#pragma unroll
    for (int m = 0; m < 4; ++m)
#pragma unroll
      for (int r = 0; r < 4; ++r) mx = fmaxf(mx, acc[m][n][r]);
    mx = fmaxf(mx, __shfl_xor(mx, 16, 64));
    mx = fmaxf(mx, __shfl_xor(mx, 32, 64));
    float s = 0.f;
#pragma unroll
    for (int m = 0; m < 4; ++m)
#pragma unroll
      for (int r = 0; r < 4; ++r) s += exp2f(acc[m][n][r] - mx);
    s += __shfl_xor(s, 16, 64);
    s += __shfl_xor(s, 32, 64);
    if ((l >> 4) == 0) {
      const int col = wc * 64 + n * 16 + l;
      colbuf[wr][col][0] = mx;
      colbuf[wr][col][1] = s;
    }
  }
  __syncthreads();

  // merge the two wave-halves, write partials (coalesced float2)
  if (t < BM) {
    float m0 = rowbuf[0][t][0], s0 = rowbuf[0][t][1];
    float m1 = rowbuf[1][t][0], s1 = rowbuf[1][t][1];
    float mm = fmaxf(m0, m1);
    float ss = s0 * exp2f(m0 - mm) + s1 * exp2f(m1 - mm);
    rowMS[(size_t)bc * N_ + br * BM + t] = make_float2(mm, ss);
  } else {
    const int c = t - BM;
    float m0 = colbuf[0][c][0], s0 = colbuf[0][c][1];
    float m1 = colbuf[1][c][0], s1 = colbuf[1][c][1];
    float mm = fmaxf(m0, m1);
    float ss = s0 * exp2f(m0 - mm) + s1 * exp2f(m1 - mm);
    colMS[(size_t)br * N_ + bc * BN + c] = make_float2(mm, ss);
  }
}

// ---------------- merge partials -> per-row/col LSE2 -> partial sums (base-2) ----------
__global__ void reduce1_kernel(const float2* __restrict__ rowMS,
                               const float2* __restrict__ colMS,
                               const float* __restrict__ diag,
                               float* __restrict__ partials) {
  const int tid = blockIdx.x * blockDim.x + threadIdx.x;  // 0..32767
  float m = -1e30f, s = 0.f;
  if (tid < N_) {
    const int r = tid;
    for (int cb = 0; cb < NBLK; ++cb) {
      float2 p = rowMS[(size_t)cb * N_ + r];
      float nm = fmaxf(m, p.x);
      s = s * exp2f(m - nm) + p.y * exp2f(p.x - nm);
      m = nm;
    }
    m = m + log2f(s) - diag[r];
  } else {
    const int c = tid - N_;
    for (int rb = 0; rb < NBLK; ++rb) {
      float2 p = colMS[(size_t)rb * N_ + c];
      float nm = fmaxf(m, p.x);
      s = s * exp2f(m - nm) + p.y * exp2f(p.x - nm);
      m = nm;
    }
    m = m + log2f(s) - diag[c];
  }
  float val = m;
#pragma unroll
  for (int off = 1; off < 64; off <<= 1) val += __shfl_xor(val, off, 64);
  __shared__ float red[4];
  if ((threadIdx.x & 63) == 0) red[threadIdx.x >> 6] = val;
  __syncthreads();
  if (threadIdx.x == 0) partials[blockIdx.x] = red[0] + red[1] + red[2] + red[3];
}

__global__ void reduce2_kernel(const float* __restrict__ partials, float* __restrict__ out) {
  const int t = threadIdx.x;  // 64 threads
  float v = partials[t] + partials[t + 64];
#pragma unroll
  for (int off = 1; off < 64; off <<= 1) v += __shfl_xor(v, off, 64);
  // base-2 -> natural log: x ln2 ; mean over rows+cols and the 0.5 factor
  if (t == 0) out[0] = v * (0.69314718055994531f / (2.0f * (float)N_));
}

extern "C" void kernel_launch(void* const* d_in, const int* in_sizes, int n_in,
                              void* d_out, int out_size, void* d_ws, size_t ws_size,
                              hipStream_t stream) {
  const float* img = (const float*)d_in[0];
  const float* txt = (const float*)d_in[1];
  const float* scale = (const float*)d_in[2];
  float* out = (float*)d_out;

  char* ws = (char*)d_ws;
  size_t off = 0;
  unsigned short* imgB = (unsigned short*)(ws + off); off += (size_t)N_ * D_ * 2;
  unsigned short* txtB = (unsigned short*)(ws + off); off += (size_t)N_ * D_ * 2;
  float2* rowMS = (float2*)(ws + off); off += (size_t)NBLK * N_ * sizeof(float2);
  float2* colMS = (float2*)(ws + off); off += (size_t)NBLK * N_ * sizeof(float2);
  float* diag = (float*)(ws + off); off += (size_t)N_ * sizeof(float);
  float* partials = (float*)(ws + off); off += 128 * sizeof(float);
  (void)ws_size; (void)in_sizes; (void)n_in; (void)out_size;

  cvt_bf16_kernel<<<1024, 256, 0, stream>>>(img, imgB, (long)N_ * D_, scale);
  cvt_bf16_kernel<<<1024, 256, 0, stream>>>(txt, txtB, (long)N_ * D_, nullptr);
  gemm_lse_kernel<<<NBLK * NBLK, 256, 0, stream>>>(imgB, txtB, rowMS, colMS, diag);
  reduce1_kernel<<<(2 * N_) / 256, 256, 0, stream>>>(rowMS, colMS, diag, partials);
  reduce2_kernel<<<1, 64, 0, stream>>>(partials, out);
}